// Round 1
// baseline (435.894 us; speedup 1.0000x reference)
//
#include <hip/hip_runtime.h>

typedef unsigned short ushort_t;
typedef __attribute__((ext_vector_type(8))) short bf16x8;
typedef __attribute__((ext_vector_type(4))) float f32x4;

__device__ __forceinline__ unsigned short f2b(float f) {
  unsigned u = __builtin_bit_cast(unsigned, f);
  u += 0x7fffu + ((u >> 16) & 1u);
  return (unsigned short)(u >> 16);
}

__device__ __forceinline__ void gload_lds16(const ushort_t* g, ushort_t* l) {
  auto* gp = (const __attribute__((address_space(1))) ushort_t*)g;
  auto* lp = (__attribute__((address_space(3))) ushort_t*)l;
  __builtin_amdgcn_global_load_lds(gp, lp, 16, 0, 0);
}

__device__ __forceinline__ void storeC(float* C, size_t i, float v) { C[i] = v; }
__device__ __forceinline__ void storeC(ushort_t* C, size_t i, float v) { C[i] = f2b(v); }

// ---------------- conversion kernels ----------------

__global__ __launch_bounds__(256) void cast_f32_bf16_k(const float4* __restrict__ in,
                                                       ushort4* __restrict__ out, int n4) {
  int i = blockIdx.x * 256 + threadIdx.x;
  if (i < n4) {
    float4 v = in[i];
    ushort4 o;
    o.x = f2b(v.x); o.y = f2b(v.y); o.z = f2b(v.z); o.w = f2b(v.w);
    out[i] = o;
  }
}

// out[c][r] = bf16(in[r][c]), per batch slice. grid=(cols/64, rows/64, batch)
__global__ __launch_bounds__(256) void transpose_cast_k(const float* __restrict__ in,
                                                        ushort_t* __restrict__ out,
                                                        int rows, int cols) {
  __shared__ float tile[64][65];
  size_t boff = (size_t)blockIdx.z * rows * cols;
  const float* inb = in + boff;
  ushort_t* outb = out + boff;
  int r0 = blockIdx.y * 64, c0 = blockIdx.x * 64;
  int lr = threadIdx.x >> 6, lc = threadIdx.x & 63;
#pragma unroll
  for (int i = 0; i < 16; i++) {
    int r = i * 4 + lr;
    tile[r][lc] = inb[(size_t)(r0 + r) * cols + (c0 + lc)];
  }
  __syncthreads();
#pragma unroll
  for (int i = 0; i < 16; i++) {
    int oc = i * 4 + lr;  // output row = original column c0+oc
    outb[(size_t)(c0 + oc) * rows + (r0 + lc)] = f2b(tile[lc][oc]);
  }
}

// ---------------- dense GEMM: C[M][N] = A[M][K] * BT[N][K]^T ----------------
// 128x128 tile, BK=32, 4 waves (2x2), 16x16x32 bf16 MFMA, m97 structure.
// LDS layout: [row][kc^((row>>1)&3)][8] (16B-chunk XOR swizzle, 2-way max).

template <typename OutT>
__global__ __launch_bounds__(256) void gemm_bt_k(const ushort_t* __restrict__ A,
                                                 const ushort_t* __restrict__ BT,
                                                 OutT* __restrict__ C, int M, int N, int K) {
  __shared__ alignas(16) ushort_t lA[128 * 32];
  __shared__ alignas(16) ushort_t lB[128 * 32];
  int tid = threadIdx.x, lane = tid & 63, wave = tid >> 6;
  int wm = wave >> 1, wn = wave & 1;
  int m0 = blockIdx.y * 128, n0 = blockIdx.x * 128;
  int lr = lane & 15, lk = lane >> 4;
  f32x4 acc[4][4] = {};
  for (int k0 = 0; k0 < K; k0 += 32) {
    __syncthreads();
#pragma unroll
    for (int t = 0; t < 2; t++) {
      int cb = wave * 128 + t * 64;
      int c = cb + lane;
      int r = c >> 2;
      int kc = (c & 3) ^ ((r >> 1) & 3);
      gload_lds16(A + (size_t)(m0 + r) * K + k0 + kc * 8, lA + (size_t)cb * 8);
      gload_lds16(BT + (size_t)(n0 + r) * K + k0 + kc * 8, lB + (size_t)cb * 8);
    }
    __syncthreads();
    bf16x8 aF[4], bF[4];
#pragma unroll
    for (int i = 0; i < 4; i++) {
      int r = wm * 64 + i * 16 + lr;
      int kc = lk ^ ((r >> 1) & 3);
      aF[i] = *(const bf16x8*)(lA + r * 32 + kc * 8);
    }
#pragma unroll
    for (int j = 0; j < 4; j++) {
      int r = wn * 64 + j * 16 + lr;
      int kc = lk ^ ((r >> 1) & 3);
      bF[j] = *(const bf16x8*)(lB + r * 32 + kc * 8);
    }
#pragma unroll
    for (int i = 0; i < 4; i++)
#pragma unroll
      for (int j = 0; j < 4; j++)
        acc[i][j] = __builtin_amdgcn_mfma_f32_16x16x32_bf16(aF[i], bF[j], acc[i][j], 0, 0, 0);
  }
#pragma unroll
  for (int i = 0; i < 4; i++) {
#pragma unroll
    for (int j = 0; j < 4; j++) {
      int row = m0 + wm * 64 + i * 16 + lk * 4;
      int col = n0 + wn * 64 + j * 16 + lr;
#pragma unroll
      for (int r = 0; r < 4; r++) storeC(C, (size_t)(row + r) * N + col, acc[i][j][r]);
    }
  }
}

// ---------------- fused per-head: mid = silu(Q Kh^T) Vh ----------------
// grid (32 q-tiles, 16 heads); block 256 (4 waves, 2x2).
// Q tile 128x128 in LDS (loaded once); loop m in steps of 64:
//   stage K[64][128] + VT[128][64] -> GEMM1 (S 128x64) -> silu -> lS -> GEMM2.

__global__ __launch_bounds__(256) void fused_mid_k(const ushort_t* __restrict__ Qb,
                                                   const ushort_t* __restrict__ Kb,
                                                   const ushort_t* __restrict__ VTb,
                                                   ushort_t* __restrict__ mid) {
  __shared__ alignas(16) ushort_t lQ[128 * 128];  // [t][dk], chunk^(t&15)
  __shared__ alignas(16) ushort_t lK[64 * 128];   // [m][dk], chunk^(m&15)
  __shared__ alignas(16) ushort_t lV[128 * 64];   // [v][m],  chunk^(v&7)
  __shared__ alignas(16) ushort_t lS[128 * 64];   // [t][m],  chunk^(t&7)
  int tid = threadIdx.x, lane = tid & 63, wave = tid >> 6;
  int wm = wave >> 1, wn = wave & 1;
  int lr = lane & 15, lk = lane >> 4;
  int t0 = blockIdx.x * 128;
  int h = blockIdx.y;
  const ushort_t* Qh = Qb + (size_t)t0 * 2048 + h * 128;
  const ushort_t* Kh = Kb + (size_t)h * 6144 * 128;
  const ushort_t* Vh = VTb + (size_t)h * 128 * 6144;

  // stage Q tile: 2048 chunks of 16B, 8 calls/wave, pre-swizzled source
#pragma unroll
  for (int t = 0; t < 8; t++) {
    int cb = (wave * 8 + t) * 64;
    int c = cb + lane;
    int r = c >> 4;
    int kc = (c & 15) ^ (r & 15);
    gload_lds16(Qh + (size_t)r * 2048 + kc * 8, lQ + (size_t)cb * 8);
  }

  f32x4 acc[4][4] = {};
  for (int m0 = 0; m0 < 6144; m0 += 64) {
    __syncthreads();
#pragma unroll
    for (int t = 0; t < 4; t++) {
      int cb = (wave * 4 + t) * 64;
      int c = cb + lane;
      int rk = c >> 4;
      int kck = (c & 15) ^ (rk & 15);
      gload_lds16(Kh + (size_t)(m0 + rk) * 128 + kck * 8, lK + (size_t)cb * 8);
      int rv = c >> 3;
      int kcv = (c & 7) ^ (rv & 7);
      gload_lds16(Vh + (size_t)rv * 6144 + m0 + kcv * 8, lV + (size_t)cb * 8);
    }
    __syncthreads();
    // GEMM1: S[128][64]; wave block rows wm*64..+64, cols wn*32..+32
    f32x4 s[4][2] = {};
#pragma unroll
    for (int ks = 0; ks < 4; ks++) {
      bf16x8 qF[4], kF[2];
#pragma unroll
      for (int i = 0; i < 4; i++) {
        int r = wm * 64 + i * 16 + lr;
        int kc = (ks * 4 + lk) ^ (r & 15);
        qF[i] = *(const bf16x8*)(lQ + r * 128 + kc * 8);
      }
#pragma unroll
      for (int j = 0; j < 2; j++) {
        int r = wn * 32 + j * 16 + lr;
        int kc = (ks * 4 + lk) ^ (r & 15);
        kF[j] = *(const bf16x8*)(lK + r * 128 + kc * 8);
      }
#pragma unroll
      for (int i = 0; i < 4; i++)
#pragma unroll
        for (int j = 0; j < 2; j++)
          s[i][j] = __builtin_amdgcn_mfma_f32_16x16x32_bf16(qF[i], kF[j], s[i][j], 0, 0, 0);
    }
    // SiLU -> lS (bf16, swizzled)
#pragma unroll
    for (int i = 0; i < 4; i++) {
#pragma unroll
      for (int j = 0; j < 2; j++) {
        int mcol = wn * 32 + j * 16 + lr;
#pragma unroll
        for (int r = 0; r < 4; r++) {
          int trow = wm * 64 + i * 16 + lk * 4 + r;
          float x = s[i][j][r];
          float sg = __builtin_amdgcn_rcpf(1.0f + __expf(-x));
          int mc = (mcol >> 3) ^ (trow & 7);
          lS[trow * 64 + mc * 8 + (mcol & 7)] = f2b(x * sg);
        }
      }
    }
    __syncthreads();
    // GEMM2: acc += S * V  (k = m, 2 k-steps)
#pragma unroll
    for (int ks = 0; ks < 2; ks++) {
      bf16x8 sF[4], vF[4];
#pragma unroll
      for (int i = 0; i < 4; i++) {
        int r = wm * 64 + i * 16 + lr;
        int kc = (ks * 4 + lk) ^ (r & 7);
        sF[i] = *(const bf16x8*)(lS + r * 64 + kc * 8);
      }
#pragma unroll
      for (int j = 0; j < 4; j++) {
        int r = wn * 64 + j * 16 + lr;
        int kc = (ks * 4 + lk) ^ (r & 7);
        vF[j] = *(const bf16x8*)(lV + r * 64 + kc * 8);
      }
#pragma unroll
      for (int i = 0; i < 4; i++)
#pragma unroll
        for (int j = 0; j < 4; j++)
          acc[i][j] = __builtin_amdgcn_mfma_f32_16x16x32_bf16(sF[i], vF[j], acc[i][j], 0, 0, 0);
    }
  }
  // epilogue: mid[t][h*128 + v] (bf16)
#pragma unroll
  for (int i = 0; i < 4; i++) {
#pragma unroll
    for (int j = 0; j < 4; j++) {
      int row = t0 + wm * 64 + i * 16 + lk * 4;
      int col = h * 128 + wn * 64 + j * 16 + lr;
#pragma unroll
      for (int r = 0; r < 4; r++) mid[(size_t)(row + r) * 2048 + col] = f2b(acc[i][j][r]);
    }
  }
}

// ---------------- host ----------------

extern "C" void kernel_launch(void* const* d_in, const int* in_sizes, int n_in,
                              void* d_out, int out_size, void* d_ws, size_t ws_size,
                              hipStream_t stream) {
  const float* x  = (const float*)d_in[0];   // (2,2048,2048) -> 4096x2048
  const float* Wq = (const float*)d_in[1];   // (2048,2048) k-major
  const float* Wo = (const float*)d_in[2];   // (2048,2048) k-major
  const float* K  = (const float*)d_in[3];   // (16,6144,128)
  const float* V  = (const float*)d_in[4];   // (16,6144,128)
  float* out = (float*)d_out;

  // workspace layout (elements of bf16/ushort):
  ushort_t* xb   = (ushort_t*)d_ws;          // 4096*2048      = 8,388,608
  ushort_t* WqT  = xb + 8388608;             // 2048*2048 (N-major)
  ushort_t* WoT  = WqT + 4194304;            // 2048*2048 (N-major)
  ushort_t* Kb   = WoT + 4194304;            // 16*6144*128
  ushort_t* VTb  = Kb + 12582912;            // 16*128*6144 (per-head V^T)
  ushort_t* Qb   = VTb + 12582912;           // 4096*2048
  ushort_t* midb = xb;                       // alias: xb dead after GEMM1
  // total ws use: (8388608+4194304*2+12582912*2+8388608)*2 B = ~100.7 MB

  cast_f32_bf16_k<<<8192, 256, 0, stream>>>((const float4*)x, (ushort4*)xb, 2097152);
  cast_f32_bf16_k<<<12288, 256, 0, stream>>>((const float4*)K, (ushort4*)Kb, 3145728);
  transpose_cast_k<<<dim3(32, 32, 1), 256, 0, stream>>>(Wq, WqT, 2048, 2048);
  transpose_cast_k<<<dim3(32, 32, 1), 256, 0, stream>>>(Wo, WoT, 2048, 2048);
  transpose_cast_k<<<dim3(2, 96, 16), 256, 0, stream>>>(V, VTb, 6144, 128);

  // Q = x @ Wq   (4096x2048x2048), bf16 out
  gemm_bt_k<ushort_t><<<dim3(16, 32), 256, 0, stream>>>(xb, WqT, Qb, 4096, 2048, 2048);
  // mid = silu(Q Kh^T) Vh, all heads
  fused_mid_k<<<dim3(32, 16), 256, 0, stream>>>(Qb, Kb, VTb, midb);
  // out = mid @ Wo  (f32 out)
  gemm_bt_k<float><<<dim3(16, 32), 256, 0, stream>>>(midb, WoT, out, 4096, 2048, 2048);
}

// Round 2
// 418.392 us; speedup vs baseline: 1.0418x; 1.0418x over previous
//
#include <hip/hip_runtime.h>

typedef unsigned short ushort_t;
typedef __attribute__((ext_vector_type(8))) short bf16x8;
typedef __attribute__((ext_vector_type(4))) float f32x4;
typedef __attribute__((ext_vector_type(2))) unsigned int u32x2;

__device__ __forceinline__ unsigned short f2b(float f) {
  unsigned u = __builtin_bit_cast(unsigned, f);
  u += 0x7fffu + ((u >> 16) & 1u);
  return (unsigned short)(u >> 16);
}

__device__ __forceinline__ float silu_f(float x) {
  // x * sigmoid(x) = x / (1 + exp2(-x*log2e))
  float e = __builtin_amdgcn_exp2f(x * -1.44269504f);
  return x * __builtin_amdgcn_rcpf(1.0f + e);
}

__device__ __forceinline__ void gload_lds16(const ushort_t* g, ushort_t* l) {
  auto* gp = (const __attribute__((address_space(1))) ushort_t*)g;
  auto* lp = (__attribute__((address_space(3))) ushort_t*)l;
  __builtin_amdgcn_global_load_lds(gp, lp, 16, 0, 0);
}

__device__ __forceinline__ void storeC(float* C, size_t i, float v) { C[i] = v; }
__device__ __forceinline__ void storeC(ushort_t* C, size_t i, float v) { C[i] = f2b(v); }

// ---------------- conversion kernels ----------------

__global__ __launch_bounds__(256) void cast_f32_bf16_k(const float4* __restrict__ in,
                                                       ushort4* __restrict__ out, int n4) {
  int i = blockIdx.x * 256 + threadIdx.x;
  if (i < n4) {
    float4 v = in[i];
    ushort4 o;
    o.x = f2b(v.x); o.y = f2b(v.y); o.z = f2b(v.z); o.w = f2b(v.w);
    out[i] = o;
  }
}

// out[c][r] = bf16(in[r][c]), per batch slice. grid=(cols/64, rows/64, batch)
__global__ __launch_bounds__(256) void transpose_cast_k(const float* __restrict__ in,
                                                        ushort_t* __restrict__ out,
                                                        int rows, int cols) {
  __shared__ float tile[64][65];
  size_t boff = (size_t)blockIdx.z * rows * cols;
  const float* inb = in + boff;
  ushort_t* outb = out + boff;
  int r0 = blockIdx.y * 64, c0 = blockIdx.x * 64;
  int lr = threadIdx.x >> 6, lc = threadIdx.x & 63;
#pragma unroll
  for (int i = 0; i < 16; i++) {
    int r = i * 4 + lr;
    tile[r][lc] = inb[(size_t)(r0 + r) * cols + (c0 + lc)];
  }
  __syncthreads();
#pragma unroll
  for (int i = 0; i < 16; i++) {
    int oc = i * 4 + lr;  // output row = original column c0+oc
    outb[(size_t)(c0 + oc) * rows + (r0 + lc)] = f2b(tile[lc][oc]);
  }
}

// ---------------- dense GEMM: C[M][N] = A[M][K] * BT[N][K]^T ----------------
// 128x128 tile, BK=32, 4 waves (2x2), 16x16x32 bf16 MFMA, m97 structure.

template <typename OutT>
__global__ __launch_bounds__(256) void gemm_bt_k(const ushort_t* __restrict__ A,
                                                 const ushort_t* __restrict__ BT,
                                                 OutT* __restrict__ C, int M, int N, int K) {
  __shared__ alignas(16) ushort_t lA[128 * 32];
  __shared__ alignas(16) ushort_t lB[128 * 32];
  int tid = threadIdx.x, lane = tid & 63, wave = tid >> 6;
  int wm = wave >> 1, wn = wave & 1;
  int m0 = blockIdx.y * 128, n0 = blockIdx.x * 128;
  int lr = lane & 15, lk = lane >> 4;
  f32x4 acc[4][4] = {};
  for (int k0 = 0; k0 < K; k0 += 32) {
    __syncthreads();
#pragma unroll
    for (int t = 0; t < 2; t++) {
      int cb = wave * 128 + t * 64;
      int c = cb + lane;
      int r = c >> 2;
      int kc = (c & 3) ^ ((r >> 1) & 3);
      gload_lds16(A + (size_t)(m0 + r) * K + k0 + kc * 8, lA + (size_t)cb * 8);
      gload_lds16(BT + (size_t)(n0 + r) * K + k0 + kc * 8, lB + (size_t)cb * 8);
    }
    __syncthreads();
    bf16x8 aF[4], bF[4];
#pragma unroll
    for (int i = 0; i < 4; i++) {
      int r = wm * 64 + i * 16 + lr;
      int kc = lk ^ ((r >> 1) & 3);
      aF[i] = *(const bf16x8*)(lA + r * 32 + kc * 8);
    }
#pragma unroll
    for (int j = 0; j < 4; j++) {
      int r = wn * 64 + j * 16 + lr;
      int kc = lk ^ ((r >> 1) & 3);
      bF[j] = *(const bf16x8*)(lB + r * 32 + kc * 8);
    }
#pragma unroll
    for (int i = 0; i < 4; i++)
#pragma unroll
      for (int j = 0; j < 4; j++)
        acc[i][j] = __builtin_amdgcn_mfma_f32_16x16x32_bf16(aF[i], bF[j], acc[i][j], 0, 0, 0);
  }
#pragma unroll
  for (int i = 0; i < 4; i++) {
#pragma unroll
    for (int j = 0; j < 4; j++) {
      int row = m0 + wm * 64 + i * 16 + lk * 4;
      int col = n0 + wn * 64 + j * 16 + lr;
#pragma unroll
      for (int r = 0; r < 4; r++) storeC(C, (size_t)(row + r) * N + col, acc[i][j][r]);
    }
  }
}

// ---------------- fused per-head: mid = silu(Q Kh^T) Vh ----------------
// 1-D grid 512, XCD-remapped: xcd = id&7 owns heads {2*xcd, 2*xcd+1}.
// block 256 (4 waves, 2x2). Q frags hoisted to registers (stationary).
// Double-buffered K/V staging with raw barriers + explicit waitcnt (2-phase).
// GEMM1 operand-swapped: D[m][t] -> per-thread 4 consecutive m at fixed t
// -> cvt_pk + ds_write_b64 into lS[t][m] (swizzled); GEMM2 reads as before.

__global__ __launch_bounds__(256) void fused_mid_k(const ushort_t* __restrict__ Qb,
                                                   const ushort_t* __restrict__ Kb,
                                                   const ushort_t* __restrict__ VTb,
                                                   ushort_t* __restrict__ mid) {
  __shared__ alignas(16) ushort_t lK[2][64 * 128];  // [m][dk], chunk^(m&15)
  __shared__ alignas(16) ushort_t lV[2][128 * 64];  // [v][m],  chunk^(v&7)
  __shared__ alignas(16) ushort_t lS[128 * 64];     // [t][m],  chunk^(t&7)
  int tid = threadIdx.x, lane = tid & 63, wave = tid >> 6;
  int wm = wave >> 1, wn = wave & 1;
  int lr = lane & 15, lk = lane >> 4;
  int id = blockIdx.x;
  int h = (id & 7) * 2 + (id >> 8);       // head; same-head blocks share an XCD
  int t0 = ((id >> 3) & 31) * 128;        // q-tile
  const ushort_t* Qh = Qb + (size_t)t0 * 2048 + h * 128;
  const ushort_t* Kh = Kb + (size_t)h * 6144 * 128;
  const ushort_t* Vh = VTb + (size_t)h * 128 * 6144;

  // Q fragments (B-operand layout): t = wm*64+i*16+lr, k = ks*32+lk*8..+8
  bf16x8 qF[4][4];
#pragma unroll
  for (int i = 0; i < 4; i++)
#pragma unroll
    for (int ks = 0; ks < 4; ks++)
      qF[i][ks] = *(const bf16x8*)(Qh + (size_t)(wm * 64 + i * 16 + lr) * 2048 + ks * 32 + lk * 8);

#define STAGE(B, M0)                                                              \
  {                                                                               \
    _Pragma("unroll") for (int t = 0; t < 4; t++) {                               \
      int cb = (wave * 4 + t) * 64;                                               \
      int c = cb + lane;                                                          \
      int rk = c >> 4;                                                            \
      int kck = (c & 15) ^ (rk & 15);                                             \
      gload_lds16(Kh + (size_t)((M0) + rk) * 128 + kck * 8, lK[B] + (size_t)cb * 8); \
      int rv = c >> 3;                                                            \
      int kcv = (c & 7) ^ (rv & 7);                                               \
      gload_lds16(Vh + (size_t)rv * 6144 + (M0) + kcv * 8, lV[B] + (size_t)cb * 8);  \
    }                                                                             \
  }

  STAGE(0, 0);

  f32x4 acc[4][4] = {};
  int cur = 0;
  for (int m0 = 0; m0 < 6144; m0 += 64, cur ^= 1) {
    // top barrier: K/V[cur] DMA complete; all waves done with prev iteration
    asm volatile("s_waitcnt vmcnt(0)" ::: "memory");
    __builtin_amdgcn_s_barrier();
    asm volatile("" ::: "memory");
    if (m0 + 64 < 6144) STAGE(cur ^ 1, m0 + 64);  // prefetch next (crosses barriers)

    // GEMM1 swapped: s2[j][i] = (K Q^T) tile; row=m (lk*4+r), col=t (lr)
    f32x4 s2[2][4] = {};
#pragma unroll
    for (int ks = 0; ks < 4; ks++) {
      bf16x8 kF[2];
#pragma unroll
      for (int j = 0; j < 2; j++) {
        int r = wn * 32 + j * 16 + lr;
        int kc = (ks * 4 + lk) ^ (r & 15);
        kF[j] = *(const bf16x8*)(lK[cur] + r * 128 + kc * 8);
      }
#pragma unroll
      for (int j = 0; j < 2; j++)
#pragma unroll
        for (int i = 0; i < 4; i++)
          s2[j][i] = __builtin_amdgcn_mfma_f32_16x16x32_bf16(kF[j], qF[i][ks], s2[j][i], 0, 0, 0);
    }
    // SiLU + pack(bf16x2) + b64 store: 4 consecutive m at fixed t
#pragma unroll
    for (int j = 0; j < 2; j++) {
#pragma unroll
      for (int i = 0; i < 4; i++) {
        int mb = wn * 32 + j * 16 + lk * 4;
        int t = wm * 64 + i * 16 + lr;
        float v0 = silu_f(s2[j][i][0]), v1 = silu_f(s2[j][i][1]);
        float v2 = silu_f(s2[j][i][2]), v3 = silu_f(s2[j][i][3]);
        unsigned d0, d1;
        asm("v_cvt_pk_bf16_f32 %0, %1, %2" : "=v"(d0) : "v"(v0), "v"(v1));
        asm("v_cvt_pk_bf16_f32 %0, %1, %2" : "=v"(d1) : "v"(v2), "v"(v3));
        int mc = (mb >> 3) ^ (t & 7);
        u32x2 val; val.x = d0; val.y = d1;
        *(u32x2*)(lS + t * 64 + mc * 8 + (mb & 7)) = val;
      }
    }
    // mid barrier: lS writes visible (keep prefetch vmcnt in flight!)
    asm volatile("s_waitcnt lgkmcnt(0)" ::: "memory");
    __builtin_amdgcn_s_barrier();
    asm volatile("" ::: "memory");
    // GEMM2: acc += S * V
#pragma unroll
    for (int ks = 0; ks < 2; ks++) {
      bf16x8 sF[4], vF[4];
#pragma unroll
      for (int i = 0; i < 4; i++) {
        int r = wm * 64 + i * 16 + lr;
        int kc = (ks * 4 + lk) ^ (r & 7);
        sF[i] = *(const bf16x8*)(lS + r * 64 + kc * 8);
      }
#pragma unroll
      for (int j = 0; j < 4; j++) {
        int r = wn * 64 + j * 16 + lr;
        int kc = (ks * 4 + lk) ^ (r & 7);
        vF[j] = *(const bf16x8*)(lV[cur] + r * 64 + kc * 8);
      }
#pragma unroll
      for (int i = 0; i < 4; i++)
#pragma unroll
        for (int j = 0; j < 4; j++)
          acc[i][j] = __builtin_amdgcn_mfma_f32_16x16x32_bf16(sF[i], vF[j], acc[i][j], 0, 0, 0);
    }
  }
#undef STAGE
  // epilogue: mid[t][h*128 + v] (bf16)
#pragma unroll
  for (int i = 0; i < 4; i++) {
#pragma unroll
    for (int j = 0; j < 4; j++) {
      int row = t0 + wm * 64 + i * 16 + lk * 4;
      int col = h * 128 + wn * 64 + j * 16 + lr;
#pragma unroll
      for (int r = 0; r < 4; r++) mid[(size_t)(row + r) * 2048 + col] = f2b(acc[i][j][r]);
    }
  }
}

// ---------------- host ----------------

extern "C" void kernel_launch(void* const* d_in, const int* in_sizes, int n_in,
                              void* d_out, int out_size, void* d_ws, size_t ws_size,
                              hipStream_t stream) {
  const float* x  = (const float*)d_in[0];   // (2,2048,2048) -> 4096x2048
  const float* Wq = (const float*)d_in[1];   // (2048,2048) k-major
  const float* Wo = (const float*)d_in[2];   // (2048,2048) k-major
  const float* K  = (const float*)d_in[3];   // (16,6144,128)
  const float* V  = (const float*)d_in[4];   // (16,6144,128)
  float* out = (float*)d_out;

  // workspace layout (elements of bf16/ushort):
  ushort_t* xb   = (ushort_t*)d_ws;          // 4096*2048
  ushort_t* WqT  = xb + 8388608;             // 2048*2048 (N-major)
  ushort_t* WoT  = WqT + 4194304;            // 2048*2048 (N-major)
  ushort_t* Kb   = WoT + 4194304;            // 16*6144*128
  ushort_t* VTb  = Kb + 12582912;            // 16*128*6144 (per-head V^T)
  ushort_t* Qb   = VTb + 12582912;           // 4096*2048
  ushort_t* midb = xb;                       // alias: xb dead after GEMM1

  cast_f32_bf16_k<<<8192, 256, 0, stream>>>((const float4*)x, (ushort4*)xb, 2097152);
  cast_f32_bf16_k<<<12288, 256, 0, stream>>>((const float4*)K, (ushort4*)Kb, 3145728);
  transpose_cast_k<<<dim3(32, 32, 1), 256, 0, stream>>>(Wq, WqT, 2048, 2048);
  transpose_cast_k<<<dim3(32, 32, 1), 256, 0, stream>>>(Wo, WoT, 2048, 2048);
  transpose_cast_k<<<dim3(2, 96, 16), 256, 0, stream>>>(V, VTb, 6144, 128);

  // Q = x @ Wq   (4096x2048x2048), bf16 out
  gemm_bt_k<ushort_t><<<dim3(16, 32), 256, 0, stream>>>(xb, WqT, Qb, 4096, 2048, 2048);
  // mid = silu(Q Kh^T) Vh, all heads
  fused_mid_k<<<512, 256, 0, stream>>>(Qb, Kb, VTb, midb);
  // out = mid @ Wo  (f32 out)
  gemm_bt_k<float><<<dim3(16, 32), 256, 0, stream>>>(midb, WoT, out, 4096, 2048, 2048);
}

// Round 3
// 379.393 us; speedup vs baseline: 1.1489x; 1.1028x over previous
//
#include <hip/hip_runtime.h>

typedef unsigned short ushort_t;
typedef __attribute__((ext_vector_type(8))) short bf16x8;
typedef __attribute__((ext_vector_type(4))) float f32x4;
typedef __attribute__((ext_vector_type(4))) unsigned int u32x4;

__device__ __forceinline__ unsigned short f2b(float f) {
  unsigned u = __builtin_bit_cast(unsigned, f);
  u += 0x7fffu + ((u >> 16) & 1u);
  return (unsigned short)(u >> 16);
}

__device__ __forceinline__ float silu_f(float x) {
  float e = __builtin_amdgcn_exp2f(x * -1.44269504f);
  return x * __builtin_amdgcn_rcpf(1.0f + e);
}

__device__ __forceinline__ void gload_lds16(const ushort_t* g, ushort_t* l) {
  auto* gp = (const __attribute__((address_space(1))) ushort_t*)g;
  auto* lp = (__attribute__((address_space(3))) ushort_t*)l;
  __builtin_amdgcn_global_load_lds(gp, lp, 16, 0, 0);
}

__device__ __forceinline__ void storeC(float* C, size_t i, float v) { C[i] = v; }
__device__ __forceinline__ void storeC(ushort_t* C, size_t i, float v) { C[i] = f2b(v); }

// ---------------- conversion kernels ----------------

__global__ __launch_bounds__(256) void cast_f32_bf16_k(const float4* __restrict__ in,
                                                       ushort4* __restrict__ out, int n4) {
  int i = blockIdx.x * 256 + threadIdx.x;
  if (i < n4) {
    float4 v = in[i];
    ushort4 o;
    o.x = f2b(v.x); o.y = f2b(v.y); o.z = f2b(v.z); o.w = f2b(v.w);
    out[i] = o;
  }
}

__global__ __launch_bounds__(256) void transpose_cast_k(const float* __restrict__ in,
                                                        ushort_t* __restrict__ out,
                                                        int rows, int cols) {
  __shared__ float tile[64][65];
  size_t boff = (size_t)blockIdx.z * rows * cols;
  const float* inb = in + boff;
  ushort_t* outb = out + boff;
  int r0 = blockIdx.y * 64, c0 = blockIdx.x * 64;
  int lr = threadIdx.x >> 6, lc = threadIdx.x & 63;
#pragma unroll
  for (int i = 0; i < 16; i++) {
    int r = i * 4 + lr;
    tile[r][lc] = inb[(size_t)(r0 + r) * cols + (c0 + lc)];
  }
  __syncthreads();
#pragma unroll
  for (int i = 0; i < 16; i++) {
    int oc = i * 4 + lr;
    outb[(size_t)(c0 + oc) * rows + (r0 + lc)] = f2b(tile[lc][oc]);
  }
}

// ---------------- dense GEMM: C[M][N] = A[M][K] * BT[N][K]^T ----------------
// 128x128 tile, BK=32, double-buffered LDS, single barrier/step, prefetch
// crosses the barrier (counted-vmcnt style: only the arriving buffer drained).

template <typename OutT>
__global__ __launch_bounds__(256) void gemm_bt_k(const ushort_t* __restrict__ A,
                                                 const ushort_t* __restrict__ BT,
                                                 OutT* __restrict__ C, int M, int N, int K) {
  __shared__ alignas(16) ushort_t lA[2][128 * 32];
  __shared__ alignas(16) ushort_t lB[2][128 * 32];
  int tid = threadIdx.x, lane = tid & 63, wave = tid >> 6;
  int wm = wave >> 1, wn = wave & 1;
  int m0 = blockIdx.y * 128, n0 = blockIdx.x * 128;
  int lr = lane & 15, lk = lane >> 4;
  f32x4 acc[4][4] = {};

#define STG(B, K0)                                                                   \
  {                                                                                  \
    _Pragma("unroll") for (int t = 0; t < 2; t++) {                                  \
      int cb = wave * 128 + t * 64;                                                  \
      int c = cb + lane;                                                             \
      int r = c >> 2;                                                                \
      int kc = (c & 3) ^ ((r >> 1) & 3);                                             \
      gload_lds16(A + (size_t)(m0 + r) * K + (K0) + kc * 8, lA[B] + (size_t)cb * 8); \
      gload_lds16(BT + (size_t)(n0 + r) * K + (K0) + kc * 8, lB[B] + (size_t)cb * 8);\
    }                                                                                \
  }

  STG(0, 0);
  int cur = 0;
  for (int k0 = 0; k0 < K; k0 += 32, cur ^= 1) {
    asm volatile("s_waitcnt vmcnt(0)" ::: "memory");
    __builtin_amdgcn_s_barrier();
    asm volatile("" ::: "memory");
    if (k0 + 32 < K) STG(cur ^ 1, k0 + 32);
    bf16x8 aF[4], bF[4];
#pragma unroll
    for (int i = 0; i < 4; i++) {
      int r = wm * 64 + i * 16 + lr;
      int kc = lk ^ ((r >> 1) & 3);
      aF[i] = *(const bf16x8*)(lA[cur] + r * 32 + kc * 8);
    }
#pragma unroll
    for (int j = 0; j < 4; j++) {
      int r = wn * 64 + j * 16 + lr;
      int kc = lk ^ ((r >> 1) & 3);
      bF[j] = *(const bf16x8*)(lB[cur] + r * 32 + kc * 8);
    }
#pragma unroll
    for (int i = 0; i < 4; i++)
#pragma unroll
      for (int j = 0; j < 4; j++)
        acc[i][j] = __builtin_amdgcn_mfma_f32_16x16x32_bf16(aF[i], bF[j], acc[i][j], 0, 0, 0);
  }
#undef STG
#pragma unroll
  for (int i = 0; i < 4; i++) {
#pragma unroll
    for (int j = 0; j < 4; j++) {
      int row = m0 + wm * 64 + i * 16 + lk * 4;
      int col = n0 + wn * 64 + j * 16 + lr;
#pragma unroll
      for (int r = 0; r < 4; r++) storeC(C, (size_t)(row + r) * N + col, acc[i][j][r]);
    }
  }
}

// ---------------- fused per-head: mid = silu(Q Kh^T) Vh ----------------
// Each wave owns a 32-row t-slice and the FULL m-range of each 64-m step.
// K-tile staged with row permutation pi(i) = [b5 | b3 b2 | b4 | b1 b0] so the
// swapped-GEMM1 output registers, after silu+cvt_pk, ARE GEMM2's A-fragments
// (m = 32*ksg + 8*lk + e lands exactly at lane quarter lk, k-slot e).
// No S round-trip through LDS; one barrier per step; K/V double-buffered.

__global__ __launch_bounds__(256) void fused_mid_k(const ushort_t* __restrict__ Qb,
                                                   const ushort_t* __restrict__ Kb,
                                                   const ushort_t* __restrict__ VTb,
                                                   ushort_t* __restrict__ mid) {
  __shared__ alignas(16) ushort_t lK[2][64 * 128];  // row i = K[m0+pi(i)], chunk^(i&15)
  __shared__ alignas(16) ushort_t lV[2][128 * 64];  // [v][m-chunk], chunk^(v&7)
  int tid = threadIdx.x, lane = tid & 63, wave = tid >> 6;
  int lr = lane & 15, lk = lane >> 4;
  int id = blockIdx.x;
  int h = (id & 7) * 2 + (id >> 8);       // same-head blocks share an XCD
  int t0 = ((id >> 3) & 31) * 128;
  const ushort_t* Qh = Qb + (size_t)t0 * 2048 + h * 128;
  const ushort_t* Kh = Kb + (size_t)h * 6144 * 128;
  const ushort_t* Vh = VTb + (size_t)h * 128 * 6144;

  // Q fragments (B-operand): t = wave*32 + tj*16 + lr, k = ks*32 + lk*8
  bf16x8 qF[2][4];
#pragma unroll
  for (int tj = 0; tj < 2; tj++)
#pragma unroll
    for (int ks = 0; ks < 4; ks++)
      qF[tj][ks] = *(const bf16x8*)(Qh + (size_t)(wave * 32 + tj * 16 + lr) * 2048 + ks * 32 + lk * 8);

#define STAGE(B, M0)                                                              \
  {                                                                               \
    _Pragma("unroll") for (int t = 0; t < 4; t++) {                               \
      int c = (wave * 4 + t) * 64 + lane;                                         \
      int ik = c >> 4;                                                            \
      int pik = (ik & 0x20) | ((ik & 0x0C) << 1) | ((ik & 0x10) >> 2) | (ik & 3); \
      int sk = (c & 15) ^ (ik & 15);                                              \
      gload_lds16(Kh + (size_t)((M0) + pik) * 128 + sk * 8, lK[B] + (size_t)c * 8); \
      int iv = c >> 3;                                                            \
      int sv = (c & 7) ^ (iv & 7);                                                \
      gload_lds16(Vh + (size_t)iv * 6144 + (M0) + sv * 8, lV[B] + (size_t)c * 8); \
    }                                                                             \
  }

  STAGE(0, 0);

  f32x4 acc[2][8] = {};
  int cur = 0;
  for (int m0 = 0; m0 < 6144; m0 += 64, cur ^= 1) {
    asm volatile("s_waitcnt vmcnt(0)" ::: "memory");
    __builtin_amdgcn_s_barrier();
    asm volatile("" ::: "memory");
    if (m0 + 64 < 6144) STAGE(cur ^ 1, m0 + 64);  // prefetch crosses the barrier

    // GEMM1 swapped: s2[mj][tj] = K-rows(pi) x Q^T; lane reg r holds
    // S[t = wave*32+tj*16+lr][m = 32(mj>>1) + 8lk + 4(mj&1) + r]
    f32x4 s2[4][2] = {};
#pragma unroll
    for (int ks = 0; ks < 4; ks++) {
      bf16x8 kF[4];
#pragma unroll
      for (int mj = 0; mj < 4; mj++)
        kF[mj] = *(const bf16x8*)(lK[cur] + (mj * 16 + lr) * 128 + (((ks * 4 + lk) ^ lr) * 8));
#pragma unroll
      for (int mj = 0; mj < 4; mj++)
#pragma unroll
        for (int tj = 0; tj < 2; tj++)
          s2[mj][tj] = __builtin_amdgcn_mfma_f32_16x16x32_bf16(kF[mj], qF[tj][ks], s2[mj][tj], 0, 0, 0);
    }
    // SiLU + pack; P[mj][tj][b] = bf16x2 of m-pair (4(mj&1)+2b) within block
    unsigned P[4][2][2];
#pragma unroll
    for (int mj = 0; mj < 4; mj++) {
#pragma unroll
      for (int tj = 0; tj < 2; tj++) {
        float v0 = silu_f(s2[mj][tj][0]), v1 = silu_f(s2[mj][tj][1]);
        float v2 = silu_f(s2[mj][tj][2]), v3 = silu_f(s2[mj][tj][3]);
        asm("v_cvt_pk_bf16_f32 %0, %1, %2" : "=v"(P[mj][tj][0]) : "v"(v0), "v"(v1));
        asm("v_cvt_pk_bf16_f32 %0, %1, %2" : "=v"(P[mj][tj][1]) : "v"(v2), "v"(v3));
      }
    }
    // GEMM2: acc += S*V; A-frag(ksg,tj) = concat(P[2ksg][tj], P[2ksg+1][tj])
#pragma unroll
    for (int ksg = 0; ksg < 2; ksg++) {
      bf16x8 aF[2];
#pragma unroll
      for (int tj = 0; tj < 2; tj++) {
        u32x4 w;
        w.x = P[2 * ksg][tj][0];
        w.y = P[2 * ksg][tj][1];
        w.z = P[2 * ksg + 1][tj][0];
        w.w = P[2 * ksg + 1][tj][1];
        aF[tj] = __builtin_bit_cast(bf16x8, w);
      }
#pragma unroll
      for (int vj = 0; vj < 8; vj++) {
        bf16x8 vF = *(const bf16x8*)(lV[cur] + (vj * 16 + lr) * 64 + (((ksg * 4 + lk) ^ (lr & 7)) * 8));
#pragma unroll
        for (int tj = 0; tj < 2; tj++)
          acc[tj][vj] = __builtin_amdgcn_mfma_f32_16x16x32_bf16(aF[tj], vF, acc[tj][vj], 0, 0, 0);
      }
    }
  }
#undef STAGE
  // epilogue: mid[t][h*128 + v]
#pragma unroll
  for (int tj = 0; tj < 2; tj++) {
#pragma unroll
    for (int vj = 0; vj < 8; vj++) {
      int row = t0 + wave * 32 + tj * 16 + lk * 4;
      int col = h * 128 + vj * 16 + lr;
#pragma unroll
      for (int r = 0; r < 4; r++) mid[(size_t)(row + r) * 2048 + col] = f2b(acc[tj][vj][r]);
    }
  }
}

// ---------------- host ----------------

extern "C" void kernel_launch(void* const* d_in, const int* in_sizes, int n_in,
                              void* d_out, int out_size, void* d_ws, size_t ws_size,
                              hipStream_t stream) {
  const float* x  = (const float*)d_in[0];
  const float* Wq = (const float*)d_in[1];
  const float* Wo = (const float*)d_in[2];
  const float* K  = (const float*)d_in[3];
  const float* V  = (const float*)d_in[4];
  float* out = (float*)d_out;

  ushort_t* xb   = (ushort_t*)d_ws;          // 4096*2048
  ushort_t* WqT  = xb + 8388608;             // 2048*2048 (N-major)
  ushort_t* WoT  = WqT + 4194304;            // 2048*2048 (N-major)
  ushort_t* Kb   = WoT + 4194304;            // 16*6144*128
  ushort_t* VTb  = Kb + 12582912;            // 16*128*6144 (per-head V^T)
  ushort_t* Qb   = VTb + 12582912;           // 4096*2048
  ushort_t* midb = xb;                       // alias: xb dead after GEMM1

  cast_f32_bf16_k<<<8192, 256, 0, stream>>>((const float4*)x, (ushort4*)xb, 2097152);
  cast_f32_bf16_k<<<12288, 256, 0, stream>>>((const float4*)K, (ushort4*)Kb, 3145728);
  transpose_cast_k<<<dim3(32, 32, 1), 256, 0, stream>>>(Wq, WqT, 2048, 2048);
  transpose_cast_k<<<dim3(32, 32, 1), 256, 0, stream>>>(Wo, WoT, 2048, 2048);
  transpose_cast_k<<<dim3(2, 96, 16), 256, 0, stream>>>(V, VTb, 6144, 128);

  gemm_bt_k<ushort_t><<<dim3(16, 32), 256, 0, stream>>>(xb, WqT, Qb, 4096, 2048, 2048);
  fused_mid_k<<<512, 256, 0, stream>>>(Qb, Kb, VTb, midb);
  gemm_bt_k<float><<<dim3(16, 32), 256, 0, stream>>>(midb, WoT, out, 4096, 2048, 2048);
}

// Round 4
// 363.127 us; speedup vs baseline: 1.2004x; 1.0448x over previous
//
#include <hip/hip_runtime.h>

typedef unsigned short ushort_t;
typedef __attribute__((ext_vector_type(8))) short bf16x8;
typedef __attribute__((ext_vector_type(4))) float f32x4;
typedef __attribute__((ext_vector_type(4))) unsigned int u32x4;

__device__ __forceinline__ unsigned short f2b(float f) {
  unsigned u = __builtin_bit_cast(unsigned, f);
  u += 0x7fffu + ((u >> 16) & 1u);
  return (unsigned short)(u >> 16);
}

__device__ __forceinline__ float silu_f(float x) {
  float e = __builtin_amdgcn_exp2f(x * -1.44269504f);
  return x * __builtin_amdgcn_rcpf(1.0f + e);
}

__device__ __forceinline__ void silu_pack(const f32x4 s, unsigned& p0, unsigned& p1) {
  float v0 = silu_f(s[0]), v1 = silu_f(s[1]), v2 = silu_f(s[2]), v3 = silu_f(s[3]);
  asm("v_cvt_pk_bf16_f32 %0, %1, %2" : "=v"(p0) : "v"(v0), "v"(v1));
  asm("v_cvt_pk_bf16_f32 %0, %1, %2" : "=v"(p1) : "v"(v2), "v"(v3));
}

__device__ __forceinline__ void gload_lds16(const ushort_t* g, ushort_t* l) {
  auto* gp = (const __attribute__((address_space(1))) ushort_t*)g;
  auto* lp = (__attribute__((address_space(3))) ushort_t*)l;
  __builtin_amdgcn_global_load_lds(gp, lp, 16, 0, 0);
}

__device__ __forceinline__ void storeC(float* C, size_t i, float v) { C[i] = v; }
__device__ __forceinline__ void storeC(ushort_t* C, size_t i, float v) { C[i] = f2b(v); }

// ---------------- conversion kernels ----------------

__global__ __launch_bounds__(256) void cast_f32_bf16_k(const float4* __restrict__ in,
                                                       ushort4* __restrict__ out, int n4) {
  int i = blockIdx.x * 256 + threadIdx.x;
  if (i < n4) {
    float4 v = in[i];
    ushort4 o;
    o.x = f2b(v.x); o.y = f2b(v.y); o.z = f2b(v.z); o.w = f2b(v.w);
    out[i] = o;
  }
}

__global__ __launch_bounds__(256) void transpose_cast_k(const float* __restrict__ in,
                                                        ushort_t* __restrict__ out,
                                                        int rows, int cols) {
  __shared__ float tile[64][65];
  size_t boff = (size_t)blockIdx.z * rows * cols;
  const float* inb = in + boff;
  ushort_t* outb = out + boff;
  int r0 = blockIdx.y * 64, c0 = blockIdx.x * 64;
  int lr = threadIdx.x >> 6, lc = threadIdx.x & 63;
#pragma unroll
  for (int i = 0; i < 16; i++) {
    int r = i * 4 + lr;
    tile[r][lc] = inb[(size_t)(r0 + r) * cols + (c0 + lc)];
  }
  __syncthreads();
#pragma unroll
  for (int i = 0; i < 16; i++) {
    int oc = i * 4 + lr;
    outb[(size_t)(c0 + oc) * rows + (r0 + lc)] = f2b(tile[lc][oc]);
  }
}

// ---------------- dense GEMM: C[M][N] = A[M][K] * BT[N][K]^T ----------------

template <typename OutT>
__global__ __launch_bounds__(256) void gemm_bt_k(const ushort_t* __restrict__ A,
                                                 const ushort_t* __restrict__ BT,
                                                 OutT* __restrict__ C, int M, int N, int K) {
  __shared__ alignas(16) ushort_t lA[2][128 * 32];
  __shared__ alignas(16) ushort_t lB[2][128 * 32];
  int tid = threadIdx.x, lane = tid & 63, wave = tid >> 6;
  int wm = wave >> 1, wn = wave & 1;
  int m0 = blockIdx.y * 128, n0 = blockIdx.x * 128;
  int lr = lane & 15, lk = lane >> 4;
  f32x4 acc[4][4] = {};

#define STG(B, K0)                                                                   \
  {                                                                                  \
    _Pragma("unroll") for (int t = 0; t < 2; t++) {                                  \
      int cb = wave * 128 + t * 64;                                                  \
      int c = cb + lane;                                                             \
      int r = c >> 2;                                                                \
      int kc = (c & 3) ^ ((r >> 1) & 3);                                             \
      gload_lds16(A + (size_t)(m0 + r) * K + (K0) + kc * 8, lA[B] + (size_t)cb * 8); \
      gload_lds16(BT + (size_t)(n0 + r) * K + (K0) + kc * 8, lB[B] + (size_t)cb * 8);\
    }                                                                                \
  }

  STG(0, 0);
  int cur = 0;
  for (int k0 = 0; k0 < K; k0 += 32, cur ^= 1) {
    asm volatile("s_waitcnt vmcnt(0)" ::: "memory");
    __builtin_amdgcn_s_barrier();
    asm volatile("" ::: "memory");
    if (k0 + 32 < K) STG(cur ^ 1, k0 + 32);
    bf16x8 aF[4], bF[4];
#pragma unroll
    for (int i = 0; i < 4; i++) {
      int r = wm * 64 + i * 16 + lr;
      int kc = lk ^ ((r >> 1) & 3);
      aF[i] = *(const bf16x8*)(lA[cur] + r * 32 + kc * 8);
    }
#pragma unroll
    for (int j = 0; j < 4; j++) {
      int r = wn * 64 + j * 16 + lr;
      int kc = lk ^ ((r >> 1) & 3);
      bF[j] = *(const bf16x8*)(lB[cur] + r * 32 + kc * 8);
    }
#pragma unroll
    for (int i = 0; i < 4; i++)
#pragma unroll
      for (int j = 0; j < 4; j++)
        acc[i][j] = __builtin_amdgcn_mfma_f32_16x16x32_bf16(aF[i], bF[j], acc[i][j], 0, 0, 0);
  }
#undef STG
#pragma unroll
  for (int i = 0; i < 4; i++) {
#pragma unroll
    for (int j = 0; j < 4; j++) {
      int row = m0 + wm * 64 + i * 16 + lk * 4;
      int col = n0 + wn * 64 + j * 16 + lr;
#pragma unroll
      for (int r = 0; r < 4; r++) storeC(C, (size_t)(row + r) * N + col, acc[i][j][r]);
    }
  }
}

// ---------------- fused per-head: mid = silu(Q Kh^T) Vh ----------------
// Wave owns 32 t-rows x full m. K rows staged via pi-permutation so GEMM1's
// swapped output (after silu+cvt_pk) IS GEMM2's A-fragment.
// Phase-split step: A = GEMM1(m 0..31); B = GEMM1(m 32..63) || silu(m 0..31);
// C = GEMM2(ksg0) || silu(m 32..63); D = GEMM2(ksg1).  Independent MFMA and
// VALU work adjacent -> matrix/VALU/trans pipes overlap within one wave.

#define MFMA_BF16 __builtin_amdgcn_mfma_f32_16x16x32_bf16

__global__ __launch_bounds__(256) void fused_mid_k(const ushort_t* __restrict__ Qb,
                                                   const ushort_t* __restrict__ Kb,
                                                   const ushort_t* __restrict__ VTb,
                                                   ushort_t* __restrict__ mid) {
  __shared__ alignas(16) ushort_t lK[2][64 * 128];  // row i = K[m0+pi(i)], chunk^(i&15)
  __shared__ alignas(16) ushort_t lV[2][128 * 64];  // [v][m-chunk], chunk^(v&7)
  int tid = threadIdx.x, lane = tid & 63, wave = tid >> 6;
  int lr = lane & 15, lk = lane >> 4;
  int id = blockIdx.x;
  int h = (id & 7) * 2 + (id >> 8);       // same-head blocks share an XCD
  int t0 = ((id >> 3) & 31) * 128;
  const ushort_t* Qh = Qb + (size_t)t0 * 2048 + h * 128;
  const ushort_t* Kh = Kb + (size_t)h * 6144 * 128;
  const ushort_t* Vh = VTb + (size_t)h * 128 * 6144;

  // Q fragments (B-operand): t = wave*32 + tj*16 + lr, k = ks*32 + lk*8
  bf16x8 qF[2][4];
#pragma unroll
  for (int tj = 0; tj < 2; tj++)
#pragma unroll
    for (int ks = 0; ks < 4; ks++)
      qF[tj][ks] = *(const bf16x8*)(Qh + (size_t)(wave * 32 + tj * 16 + lr) * 2048 + ks * 32 + lk * 8);

#define STAGE(B, M0)                                                              \
  {                                                                               \
    _Pragma("unroll") for (int t = 0; t < 4; t++) {                               \
      int c = (wave * 4 + t) * 64 + lane;                                         \
      int ik = c >> 4;                                                            \
      int pik = (ik & 0x20) | ((ik & 0x0C) << 1) | ((ik & 0x10) >> 2) | (ik & 3); \
      int sk = (c & 15) ^ (ik & 15);                                              \
      gload_lds16(Kh + (size_t)((M0) + pik) * 128 + sk * 8, lK[B] + (size_t)c * 8); \
      int iv = c >> 3;                                                            \
      int sv = (c & 7) ^ (iv & 7);                                                \
      gload_lds16(Vh + (size_t)iv * 6144 + (M0) + sv * 8, lV[B] + (size_t)c * 8); \
    }                                                                             \
  }

  STAGE(0, 0);

  f32x4 acc[2][8] = {};
  int cur = 0;
  for (int m0 = 0; m0 < 6144; m0 += 64, cur ^= 1) {
    asm volatile("s_waitcnt vmcnt(0)" ::: "memory");
    __builtin_amdgcn_s_barrier();
    asm volatile("" ::: "memory");
    if (m0 + 64 < 6144) STAGE(cur ^ 1, m0 + 64);  // prefetch crosses the barrier

    __builtin_amdgcn_s_setprio(1);
    f32x4 s2[4][2] = {};
    unsigned P[4][2][2];
    // Phase A: GEMM1, m-rows 0..31 (mj 0,1) — 16 MFMA
#pragma unroll
    for (int ks = 0; ks < 4; ks++) {
      bf16x8 k0 = *(const bf16x8*)(lK[cur] + (0 * 16 + lr) * 128 + (((ks * 4 + lk) ^ lr) * 8));
      bf16x8 k1 = *(const bf16x8*)(lK[cur] + (1 * 16 + lr) * 128 + (((ks * 4 + lk) ^ lr) * 8));
      s2[0][0] = MFMA_BF16(k0, qF[0][ks], s2[0][0], 0, 0, 0);
      s2[0][1] = MFMA_BF16(k0, qF[1][ks], s2[0][1], 0, 0, 0);
      s2[1][0] = MFMA_BF16(k1, qF[0][ks], s2[1][0], 0, 0, 0);
      s2[1][1] = MFMA_BF16(k1, qF[1][ks], s2[1][1], 0, 0, 0);
    }
    // Phase B: GEMM1 m-rows 32..63 (mj 2,3) with silu(mj 0,1) interleaved
#pragma unroll
    for (int ks = 0; ks < 4; ks++) {
      bf16x8 k2 = *(const bf16x8*)(lK[cur] + (2 * 16 + lr) * 128 + (((ks * 4 + lk) ^ lr) * 8));
      bf16x8 k3 = *(const bf16x8*)(lK[cur] + (3 * 16 + lr) * 128 + (((ks * 4 + lk) ^ lr) * 8));
      s2[2][0] = MFMA_BF16(k2, qF[0][ks], s2[2][0], 0, 0, 0);
      s2[2][1] = MFMA_BF16(k2, qF[1][ks], s2[2][1], 0, 0, 0);
      s2[3][0] = MFMA_BF16(k3, qF[0][ks], s2[3][0], 0, 0, 0);
      s2[3][1] = MFMA_BF16(k3, qF[1][ks], s2[3][1], 0, 0, 0);
      {
        int mj = ks >> 1, tjj = ks & 1;  // (0,0),(0,1),(1,0),(1,1)
        silu_pack(s2[mj][tjj], P[mj][tjj][0], P[mj][tjj][1]);
      }
    }
    // Phase C: GEMM2 ksg0 with silu(mj 2,3) interleaved
    bf16x8 aF0[2];
#pragma unroll
    for (int tj = 0; tj < 2; tj++) {
      u32x4 w;
      w.x = P[0][tj][0]; w.y = P[0][tj][1]; w.z = P[1][tj][0]; w.w = P[1][tj][1];
      aF0[tj] = __builtin_bit_cast(bf16x8, w);
    }
#pragma unroll
    for (int vj = 0; vj < 8; vj++) {
      bf16x8 vF = *(const bf16x8*)(lV[cur] + (vj * 16 + lr) * 64 + ((lk ^ (lr & 7)) * 8));
      acc[0][vj] = MFMA_BF16(aF0[0], vF, acc[0][vj], 0, 0, 0);
      acc[1][vj] = MFMA_BF16(aF0[1], vF, acc[1][vj], 0, 0, 0);
      if (vj < 4) {
        int mj = 2 + (vj >> 1), tjj = vj & 1;  // (2,0),(2,1),(3,0),(3,1)
        silu_pack(s2[mj][tjj], P[mj][tjj][0], P[mj][tjj][1]);
      }
    }
    // Phase D: GEMM2 ksg1
    bf16x8 aF1[2];
#pragma unroll
    for (int tj = 0; tj < 2; tj++) {
      u32x4 w;
      w.x = P[2][tj][0]; w.y = P[2][tj][1]; w.z = P[3][tj][0]; w.w = P[3][tj][1];
      aF1[tj] = __builtin_bit_cast(bf16x8, w);
    }
#pragma unroll
    for (int vj = 0; vj < 8; vj++) {
      bf16x8 vF = *(const bf16x8*)(lV[cur] + (vj * 16 + lr) * 64 + (((4 + lk) ^ (lr & 7)) * 8));
      acc[0][vj] = MFMA_BF16(aF1[0], vF, acc[0][vj], 0, 0, 0);
      acc[1][vj] = MFMA_BF16(aF1[1], vF, acc[1][vj], 0, 0, 0);
    }
    __builtin_amdgcn_s_setprio(0);
  }
#undef STAGE
  // epilogue: mid[t][h*128 + v]
#pragma unroll
  for (int tj = 0; tj < 2; tj++) {
#pragma unroll
    for (int vj = 0; vj < 8; vj++) {
      int row = t0 + wave * 32 + tj * 16 + lk * 4;
      int col = h * 128 + vj * 16 + lr;
#pragma unroll
      for (int r = 0; r < 4; r++) mid[(size_t)(row + r) * 2048 + col] = f2b(acc[tj][vj][r]);
    }
  }
}

// ---------------- host ----------------

extern "C" void kernel_launch(void* const* d_in, const int* in_sizes, int n_in,
                              void* d_out, int out_size, void* d_ws, size_t ws_size,
                              hipStream_t stream) {
  const float* x  = (const float*)d_in[0];
  const float* Wq = (const float*)d_in[1];
  const float* Wo = (const float*)d_in[2];
  const float* K  = (const float*)d_in[3];
  const float* V  = (const float*)d_in[4];
  float* out = (float*)d_out;

  ushort_t* xb   = (ushort_t*)d_ws;          // 4096*2048
  ushort_t* WqT  = xb + 8388608;             // 2048*2048 (N-major)
  ushort_t* WoT  = WqT + 4194304;            // 2048*2048 (N-major)
  ushort_t* Kb   = WoT + 4194304;            // 16*6144*128
  ushort_t* VTb  = Kb + 12582912;            // 16*128*6144 (per-head V^T)
  ushort_t* Qb   = VTb + 12582912;           // 4096*2048
  ushort_t* midb = xb;                       // alias: xb dead after GEMM1

  cast_f32_bf16_k<<<8192, 256, 0, stream>>>((const float4*)x, (ushort4*)xb, 2097152);
  cast_f32_bf16_k<<<12288, 256, 0, stream>>>((const float4*)K, (ushort4*)Kb, 3145728);
  transpose_cast_k<<<dim3(32, 32, 1), 256, 0, stream>>>(Wq, WqT, 2048, 2048);
  transpose_cast_k<<<dim3(32, 32, 1), 256, 0, stream>>>(Wo, WoT, 2048, 2048);
  transpose_cast_k<<<dim3(2, 96, 16), 256, 0, stream>>>(V, VTb, 6144, 128);

  gemm_bt_k<ushort_t><<<dim3(16, 32), 256, 0, stream>>>(xb, WqT, Qb, 4096, 2048, 2048);
  fused_mid_k<<<512, 256, 0, stream>>>(Qb, Kb, VTb, midb);
  gemm_bt_k<float><<<dim3(16, 32), 256, 0, stream>>>(midb, WoT, out, 4096, 2048, 2048);
}